// Round 3
// baseline (418.734 us; speedup 1.0000x reference)
//
#include <hip/hip_runtime.h>
#include <hip/hip_bf16.h>

typedef unsigned short u16;
typedef unsigned int u32;
typedef __attribute__((ext_vector_type(8))) short bf16x8;
typedef __attribute__((ext_vector_type(4))) float f32x4;
typedef __attribute__((ext_vector_type(4))) u16 u16x4;

#define NPATCH 81920
#define NBATCH 4
#define DLAT 32
#define HID 128
#define NROWS (NBATCH * NPATCH)   // 327680
#define CHUNK 128
#define NCHUNK (NROWS / CHUNK)    // 2560
#define CPB (NPATCH / CHUNK)      // 640
#define STEPGRID 512              // 2 blocks/CU * 256 CUs

// ---------- conversion helpers ----------
__device__ __forceinline__ u32 f2u(float f) { union { float f; u32 u; } c; c.f = f; return c.u; }
__device__ __forceinline__ float u2f(u32 u) { union { u32 u; float f; } c; c.u = u; return c.f; }
__device__ __forceinline__ u16 bf_rne(float x) {   // old-path helper (integer RNE)
  u32 u = f2u(x);
  return (u16)((u + 0x7FFFu + ((u >> 16) & 1u)) >> 16);
}
__device__ __forceinline__ u16 f2bf(float x) {     // native cast (RNE on gfx950)
  union { __hip_bfloat16 b; u16 u; } c; c.b = __float2bfloat16(x); return c.u;
}
__device__ __forceinline__ float bf2f(u16 h) {
  union { __hip_bfloat16 b; u16 u; } c; c.u = h; return __bfloat162float(c.b);
}

// async global->LDS DMA, 16B per lane, dest = wave-uniform base + lane*16
#define GLD(g, l) __builtin_amdgcn_global_load_lds( \
    (const __attribute__((address_space(1))) void*)(g), \
    (__attribute__((address_space(3))) void*)(l), 16, 0, 0)

// ================= NEW PATH =================
// wf  layout: [part(2)][kg(16)][n(128)][j(8)]  (k' = kg*8+j = s*32+d -> W1 row d*4+s)
// w2f layout: [part(2)][kt(4)][lg(4)][o(16)][j(8)]  (k = kt*32+lg*8+j, col o)
__global__ void prep_w(const float* __restrict__ W1, const float* __restrict__ W2,
                       u16* __restrict__ wf, u16* __restrict__ w2f) {
  int t = blockIdx.x * 256 + threadIdx.x;
  if (t < 128 * 128) {
    int kp = t >> 7, n = t & 127;
    int s = kp >> 5, d = kp & 31;
    float v = W1[(d * 4 + s) * HID + n];
    u16 h = f2bf(v);
    u16 l = f2bf(v - bf2f(h));
    int kg = kp >> 3, j = kp & 7;
    int o = (kg * 128 + n) * 8 + j;
    wf[o] = h;
    wf[16384 + o] = l;
  } else if (t < 128 * 128 + 2048) {
    int u = t - 128 * 128;            // u = k*16 + o
    int k = u >> 4, o = u & 15;
    float v = W2[k * 16 + o];
    u16 h = f2bf(v);
    u16 l = f2bf(v - bf2f(h));
    int kt = k >> 5, lg = (k >> 3) & 3, j = k & 7;
    int idx = ((kt * 4 + lg) * 16 + o) * 8 + j;
    w2f[idx] = h;
    w2f[2048 + idx] = l;
  }
}

// split z_old: dims 0..15 -> DA (dynamic, ping-pong), dims 16..31 -> S (static)
// row layout in each: [hi(16 u16)][lo(16 u16)] = 64B
__global__ void prep_z(const float* __restrict__ z, u16* __restrict__ DA, u16* __restrict__ S) {
  int t = blockIdx.x * 256 + threadIdx.x;
  if (t >= NROWS * 8) return;
  size_t row = (size_t)(t >> 3);
  int q = t & 7;                       // dim quad 0..7
  float4 v = *(const float4*)&z[row * 32 + q * 4];
  u16 h0 = f2bf(v.x), h1 = f2bf(v.y), h2 = f2bf(v.z), h3 = f2bf(v.w);
  u16 l0 = f2bf(v.x - bf2f(h0)), l1 = f2bf(v.y - bf2f(h1));
  u16 l2 = f2bf(v.z - bf2f(h2)), l3 = f2bf(v.w - bf2f(h3));
  u16* buf = (q < 4) ? DA : S;
  int qq = q & 3;
  u16x4 hh = {h0, h1, h2, h3};
  u16x4 ll = {l0, l1, l2, l3};
  *(u16x4*)&buf[row * 32 + qq * 4] = hh;
  *(u16x4*)&buf[row * 32 + 16 + qq * 4] = ll;
}

// one solver step; zf = f32 carry for dims0-15, stored stride-32 in d_out
template<int FIRST, int LAST>
__global__ __launch_bounds__(256, 2) void step_kernel(
    const u16* __restrict__ dIn, u16* __restrict__ dOut,
    const u16* __restrict__ S, const float* __restrict__ zold,
    float* __restrict__ zf, const int* __restrict__ nl,
    const float* __restrict__ b1, const float* __restrict__ b2,
    const u16* __restrict__ wf, const u16* __restrict__ w2f) {
  // A (then h) tiles in fragment order [kg(16)][row(128)][j(8)]
  __shared__ __align__(16) u16 AH[4 * 4 * 128 * 8];   // 32 KB
  __shared__ __align__(16) u16 AL[4 * 4 * 128 * 8];   // 32 KB
  __shared__ __align__(16) u16 W2H[2048];             // [kt][lg][o(16)][j] 4 KB
  __shared__ __align__(16) u16 W2L[2048];             // 4 KB

  const int tid = threadIdx.x;
  const int lane = tid & 63;
  const int w = tid >> 6;
  const int li = lane & 15;
  const int lg = lane >> 4;

  // stage W2 fragments (linear copy; 2*2048 elems = 512 slots of 8)
  #pragma unroll
  for (int c = 0; c < 2; ++c) {
    int idx = tid + c * 256;             // 0..511
    int part = idx >> 8, slot = idx & 255;
    u16* dst = part ? W2L : W2H;
    *(bf16x8*)&dst[slot * 8] = *(const bf16x8*)&w2f[part * 2048 + slot * 8];
  }

  // W1 fragments resident in registers: wave w owns cols [32w, 32w+32)
  bf16x8 WH[2][4], WL[2][4];
  #pragma unroll
  for (int nt = 0; nt < 2; ++nt)
    #pragma unroll
    for (int kt = 0; kt < 4; ++kt) {
      int kg = kt * 4 + lg;
      int n = w * 32 + nt * 16 + li;
      WH[nt][kt] = *(const bf16x8*)&wf[(kg * 128 + n) * 8];
      WL[nt][kt] = *(const bf16x8*)&wf[16384 + (kg * 128 + n) * 8];
    }

  float b1v[2][4];
  #pragma unroll
  for (int nt = 0; nt < 2; ++nt)
    #pragma unroll
    for (int r = 0; r < 4; ++r)
      b1v[nt][r] = b1[w * 32 + nt * 16 + lg * 4 + r];
  float b2v = b2[li];

  for (int chunk = blockIdx.x; chunk < NCHUNK; chunk += gridDim.x) {
    int b = chunk / CPB;
    int row0 = chunk * CHUNK;
    int pbase = row0 - b * NPATCH;
    size_t rb = (size_t)b * NPATCH;

    __syncthreads();  // prev chunk's LDS reads done (covers W2 staging on iter 0)

    // ---- gather staging: pure DMA, wave w = source section (kt=w) ----
    #pragma unroll
    for (int it = 0; it < 2; ++it) {
      int rl = it * 64 + lane;
      int p = pbase + rl;
      int ps = p;
      if (w) ps = nl[p * 3 + (w - 1)];
      const u16* dsrc = dIn + (rb + (size_t)ps) * 32;
      const u16* ssrc = S + (rb + (size_t)ps) * 32;
      int db = ((w * 4) * 128 + it * 64) * 8;   // base (elems); q slot adds q*1024
      GLD(dsrc + 0,  &AH[db + 0 * 1024]);       // q=0: dims 0-7   hi
      GLD(dsrc + 8,  &AH[db + 1 * 1024]);       // q=1: dims 8-15  hi
      GLD(ssrc + 0,  &AH[db + 2 * 1024]);       // q=2: dims 16-23 hi
      GLD(ssrc + 8,  &AH[db + 3 * 1024]);       // q=3: dims 24-31 hi
      GLD(dsrc + 16, &AL[db + 0 * 1024]);       // lo parts
      GLD(dsrc + 24, &AL[db + 1 * 1024]);
      GLD(ssrc + 16, &AL[db + 2 * 1024]);
      GLD(ssrc + 24, &AL[db + 3 * 1024]);
    }
    __syncthreads();  // compiler drains vmcnt(0) here

    // ---- GEMM1 (transposed): D[n][m] = W1^T @ A^T, bf16x3 split ----
    f32x4 acc[2][8];
    #pragma unroll
    for (int nt = 0; nt < 2; ++nt)
      #pragma unroll
      for (int mt = 0; mt < 8; ++mt)
        acc[nt][mt] = (f32x4){0.f, 0.f, 0.f, 0.f};

    #pragma unroll
    for (int kt = 0; kt < 4; ++kt) {
      #pragma unroll
      for (int mt = 0; mt < 8; ++mt) {
        int off = ((kt * 4 + lg) * 128 + mt * 16 + li) * 8;
        bf16x8 ah = *(const bf16x8*)&AH[off];
        bf16x8 al = *(const bf16x8*)&AL[off];
        #pragma unroll
        for (int nt = 0; nt < 2; ++nt) {
          acc[nt][mt] = __builtin_amdgcn_mfma_f32_16x16x32_bf16(WH[nt][kt], ah, acc[nt][mt], 0, 0, 0);
          acc[nt][mt] = __builtin_amdgcn_mfma_f32_16x16x32_bf16(WH[nt][kt], al, acc[nt][mt], 0, 0, 0);
          acc[nt][mt] = __builtin_amdgcn_mfma_f32_16x16x32_bf16(WL[nt][kt], ah, acc[nt][mt], 0, 0, 0);
        }
      }
    }
    __syncthreads();  // all A reads done before h overwrites

    // ---- bias + tanh + split -> h fragments (overwrite AH/AL) ----
    #pragma unroll
    for (int nt = 0; nt < 2; ++nt) {
      #pragma unroll
      for (int mt = 0; mt < 8; ++mt) {
        u16 hh[4], ll[4];
        #pragma unroll
        for (int r = 0; r < 4; ++r) {
          float hval = acc[nt][mt][r] + b1v[nt][r];
          float e = __expf(2.0f * hval);
          float t = 1.0f - 2.0f / (e + 1.0f);
          hh[r] = f2bf(t);
          ll[r] = f2bf(t - bf2f(hh[r]));
        }
        // n = w*32 + nt*16 + lg*4 + r  ->  [kg2 = n>>3][row=m][j = n&7]
        int base = ((w * 4 + nt * 2 + (lg >> 1)) * 128 + mt * 16 + li) * 8 + (lg & 1) * 4;
        u16x4 hv = {hh[0], hh[1], hh[2], hh[3]};
        u16x4 lv = {ll[0], ll[1], ll[2], ll[3]};
        *(u16x4*)&AH[base] = hv;
        *(u16x4*)&AL[base] = lv;
      }
    }
    __syncthreads();

    // ---- GEMM2: F[m][o] = h @ W2, bf16x3 split ----
    f32x4 acc2[2];
    acc2[0] = (f32x4){0.f, 0.f, 0.f, 0.f};
    acc2[1] = (f32x4){0.f, 0.f, 0.f, 0.f};
    #pragma unroll
    for (int kt = 0; kt < 4; ++kt) {
      int woff = ((kt * 4 + lg) * 16 + li) * 8;
      bf16x8 wh = *(const bf16x8*)&W2H[woff];
      bf16x8 wl = *(const bf16x8*)&W2L[woff];
      #pragma unroll
      for (int mt = 0; mt < 2; ++mt) {
        int off = ((kt * 4 + lg) * 128 + w * 32 + mt * 16 + li) * 8;
        bf16x8 hh = *(const bf16x8*)&AH[off];
        bf16x8 hl = *(const bf16x8*)&AL[off];
        acc2[mt] = __builtin_amdgcn_mfma_f32_16x16x32_bf16(hh, wh, acc2[mt], 0, 0, 0);
        acc2[mt] = __builtin_amdgcn_mfma_f32_16x16x32_bf16(hl, wh, acc2[mt], 0, 0, 0);
        acc2[mt] = __builtin_amdgcn_mfma_f32_16x16x32_bf16(hh, wl, acc2[mt], 0, 0, 0);
      }
    }

    // ---- epilogue ----
    #pragma unroll
    for (int mt = 0; mt < 2; ++mt) {
      #pragma unroll
      for (int r = 0; r < 4; ++r) {
        int rowg = row0 + w * 32 + mt * 16 + lg * 4 + r;
        float F = acc2[mt][r] + b2v;
        float zi = FIRST ? zold[(size_t)rowg * 32 + li] : zf[(size_t)rowg * 32 + li];
        float v = zi + F;
        zf[(size_t)rowg * 32 + li] = v;             // f32 carry (and final dims0-15)
        if (LAST) {
          zf[(size_t)rowg * 32 + 16 + li] = zold[(size_t)rowg * 32 + 16 + li];
        } else {
          u16 h = f2bf(v);
          dOut[(size_t)rowg * 32 + li] = h;
          dOut[(size_t)rowg * 32 + 16 + li] = f2bf(v - bf2f(h));
        }
      }
    }
  }
}

// ================= OLD PATH (round-1, fallback if ws too small) =================
#define SA 136
__global__ void prep_old(const float* __restrict__ W1, const float* __restrict__ W2,
                         u16* __restrict__ wf, u16* __restrict__ w2t) {
  int t = blockIdx.x * 256 + threadIdx.x;
  if (t < 128 * 128) {
    int kp = t >> 7, n = t & 127;
    int s = kp >> 5, d = kp & 31;
    float v = W1[(d * 4 + s) * HID + n];
    u16 h = bf_rne(v);
    float rem = v - u2f((u32)h << 16);
    u16 l = bf_rne(rem);
    int kg = kp >> 3, j = kp & 7;
    int o = (kg * 128 + n) * 8 + j;
    wf[o] = h;
    wf[16384 + o] = l;
  } else if (t < 128 * 128 + 128 * 16) {
    int uu = t - 128 * 128;
    int k = uu >> 4, o = uu & 15;
    float v = W2[k * 16 + o];
    u16 h = bf_rne(v);
    float rem = v - u2f((u32)h << 16);
    u16 l = bf_rne(rem);
    w2t[o * 128 + k] = h;
    w2t[2048 + o * 128 + k] = l;
  }
}

__global__ __launch_bounds__(256, 2) void step_old(
    const float* __restrict__ zin, float* __restrict__ zout,
    const int* __restrict__ nl, const float* __restrict__ b1,
    const float* __restrict__ b2, const u16* __restrict__ wf,
    const u16* __restrict__ w2t) {
  __shared__ __align__(16) u16 AH[CHUNK * SA];
  __shared__ __align__(16) u16 AL[CHUNK * SA];
  __shared__ __align__(16) u16 W2H[16 * SA];
  __shared__ __align__(16) u16 W2L[16 * SA];
  const int tid = threadIdx.x;
  const int lane = tid & 63;
  const int w = tid >> 6;
  const int li = lane & 15;
  const int lg = lane >> 4;
  #pragma unroll
  for (int c = 0; c < 2; ++c) {
    int idx = tid * 2 + c;
    int part = idx >> 8, rest = idx & 255;
    int o = rest >> 4, kc = rest & 15;
    bf16x8 v = *(const bf16x8*)&w2t[part * 2048 + o * 128 + kc * 8];
    u16* dst = part ? W2L : W2H;
    *(bf16x8*)&dst[o * SA + kc * 8] = v;
  }
  bf16x8 WH[2][4], WL[2][4];
  #pragma unroll
  for (int nt = 0; nt < 2; ++nt)
    #pragma unroll
    for (int kt = 0; kt < 4; ++kt) {
      int kg = kt * 4 + lg;
      int n = w * 32 + nt * 16 + li;
      WH[nt][kt] = *(const bf16x8*)&wf[(kg * 128 + n) * 8];
      WL[nt][kt] = *(const bf16x8*)&wf[16384 + (kg * 128 + n) * 8];
    }
  float b1v[2][4];
  #pragma unroll
  for (int nt = 0; nt < 2; ++nt)
    #pragma unroll
    for (int r = 0; r < 4; ++r)
      b1v[nt][r] = b1[w * 32 + nt * 16 + lg * 4 + r];
  float b2v = b2[li];
  for (int chunk = blockIdx.x; chunk < NCHUNK; chunk += gridDim.x) {
    int b = chunk / CPB;
    int row0 = chunk * CHUNK;
    int pbase = row0 - b * NPATCH;
    const float* zb = zin + (size_t)b * NPATCH * DLAT;
    __syncthreads();
    #pragma unroll
    for (int it = 0; it < 2; ++it) {
      int rl = it * 64 + lane;
      int p = pbase + rl;
      int ps = (w == 0) ? p : nl[p * 3 + (w - 1)];
      const float* src = zb + (size_t)ps * DLAT;
      float xs[32];
      #pragma unroll
      for (int q = 0; q < 8; ++q) {
        float4 vv = *(const float4*)&src[q * 4];
        xs[q * 4 + 0] = vv.x; xs[q * 4 + 1] = vv.y;
        xs[q * 4 + 2] = vv.z; xs[q * 4 + 3] = vv.w;
      }
      if (w == 0) {
        float* dsto = zout + (size_t)(row0 + rl) * DLAT;
        *(float4*)&dsto[16] = make_float4(xs[16], xs[17], xs[18], xs[19]);
        *(float4*)&dsto[20] = make_float4(xs[20], xs[21], xs[22], xs[23]);
        *(float4*)&dsto[24] = make_float4(xs[24], xs[25], xs[26], xs[27]);
        *(float4*)&dsto[28] = make_float4(xs[28], xs[29], xs[30], xs[31]);
      }
      int base = rl * SA + w * 32;
      #pragma unroll
      for (int q = 0; q < 4; ++q) {
        bf16x8 hv, lv;
        #pragma unroll
        for (int e = 0; e < 8; ++e) {
          float x = xs[q * 8 + e];
          u16 h = bf_rne(x);
          float rem = x - u2f((u32)h << 16);
          hv[e] = (short)h;
          lv[e] = (short)bf_rne(rem);
        }
        *(bf16x8*)&AH[base + q * 8] = hv;
        *(bf16x8*)&AL[base + q * 8] = lv;
      }
    }
    __syncthreads();
    f32x4 acc[2][8];
    #pragma unroll
    for (int nt = 0; nt < 2; ++nt)
      #pragma unroll
      for (int mt = 0; mt < 8; ++mt)
        acc[nt][mt] = (f32x4){0.f, 0.f, 0.f, 0.f};
    #pragma unroll
    for (int kt = 0; kt < 4; ++kt) {
      #pragma unroll
      for (int mt = 0; mt < 8; ++mt) {
        int off = (mt * 16 + li) * SA + kt * 32 + lg * 8;
        bf16x8 ah = *(const bf16x8*)&AH[off];
        bf16x8 al = *(const bf16x8*)&AL[off];
        #pragma unroll
        for (int nt = 0; nt < 2; ++nt) {
          acc[nt][mt] = __builtin_amdgcn_mfma_f32_16x16x32_bf16(WH[nt][kt], ah, acc[nt][mt], 0, 0, 0);
          acc[nt][mt] = __builtin_amdgcn_mfma_f32_16x16x32_bf16(WH[nt][kt], al, acc[nt][mt], 0, 0, 0);
          acc[nt][mt] = __builtin_amdgcn_mfma_f32_16x16x32_bf16(WL[nt][kt], ah, acc[nt][mt], 0, 0, 0);
        }
      }
    }
    __syncthreads();
    #pragma unroll
    for (int nt = 0; nt < 2; ++nt) {
      #pragma unroll
      for (int mt = 0; mt < 8; ++mt) {
        u16 hh[4], ll[4];
        #pragma unroll
        for (int r = 0; r < 4; ++r) {
          float hval = acc[nt][mt][r] + b1v[nt][r];
          float e = __expf(2.0f * hval);
          float t = 1.0f - 2.0f / (e + 1.0f);
          u16 hb = bf_rne(t);
          float rem = t - u2f((u32)hb << 16);
          hh[r] = hb;
          ll[r] = bf_rne(rem);
        }
        u32 hw0 = (u32)hh[0] | ((u32)hh[1] << 16);
        u32 hw1 = (u32)hh[2] | ((u32)hh[3] << 16);
        u32 lw0 = (u32)ll[0] | ((u32)ll[1] << 16);
        u32 lw1 = (u32)ll[2] | ((u32)ll[3] << 16);
        int m = mt * 16 + li;
        int n = w * 32 + nt * 16 + lg * 4;
        uint2 hv2; hv2.x = hw0; hv2.y = hw1;
        uint2 lv2; lv2.x = lw0; lv2.y = lw1;
        *(uint2*)&AH[m * SA + n] = hv2;
        *(uint2*)&AL[m * SA + n] = lv2;
      }
    }
    __syncthreads();
    f32x4 acc2[2];
    acc2[0] = (f32x4){0.f, 0.f, 0.f, 0.f};
    acc2[1] = (f32x4){0.f, 0.f, 0.f, 0.f};
    #pragma unroll
    for (int kt = 0; kt < 4; ++kt) {
      int woff = li * SA + kt * 32 + lg * 8;
      bf16x8 wh = *(const bf16x8*)&W2H[woff];
      bf16x8 wl = *(const bf16x8*)&W2L[woff];
      #pragma unroll
      for (int mt = 0; mt < 2; ++mt) {
        int off = (w * 32 + mt * 16 + li) * SA + kt * 32 + lg * 8;
        bf16x8 hh = *(const bf16x8*)&AH[off];
        bf16x8 hl = *(const bf16x8*)&AL[off];
        acc2[mt] = __builtin_amdgcn_mfma_f32_16x16x32_bf16(hh, wh, acc2[mt], 0, 0, 0);
        acc2[mt] = __builtin_amdgcn_mfma_f32_16x16x32_bf16(hl, wh, acc2[mt], 0, 0, 0);
        acc2[mt] = __builtin_amdgcn_mfma_f32_16x16x32_bf16(hh, wl, acc2[mt], 0, 0, 0);
      }
    }
    #pragma unroll
    for (int mt = 0; mt < 2; ++mt) {
      #pragma unroll
      for (int r = 0; r < 4; ++r) {
        int rowg = row0 + w * 32 + mt * 16 + lg * 4 + r;
        float F = acc2[mt][r] + b2v;
        size_t oi = (size_t)rowg * DLAT + li;
        zout[oi] = zin[oi] + F;
      }
    }
  }
}

extern "C" void kernel_launch(void* const* d_in, const int* in_sizes, int n_in,
                              void* d_out, int out_size, void* d_ws, size_t ws_size,
                              hipStream_t stream) {
  const float* z_old = (const float*)d_in[0];
  const int* nl = (const int*)d_in[1];
  const float* W1 = (const float*)d_in[2];
  const float* b1 = (const float*)d_in[3];
  const float* W2 = (const float*)d_in[4];
  const float* b2 = (const float*)d_in[5];
  float* out = (float*)d_out;

  const size_t Dbytes = (size_t)NROWS * 32 * sizeof(u16);   // 20,971,520
  const size_t need = 73728 + 3 * Dbytes;                   // ~60.1 MB

  if (ws_size >= need) {
    u16* wf = (u16*)d_ws;                     // 64 KB
    u16* w2f = wf + 32768;                    // 8 KB
    char* base = (char*)d_ws + 73728;
    u16* S  = (u16*)base;                     // static dims 16-31 split
    u16* DA = (u16*)(base + Dbytes);          // dynamic dims 0-15 split (ping)
    u16* DB = (u16*)(base + 2 * Dbytes);      // (pong)

    prep_w<<<72, 256, 0, stream>>>(W1, W2, wf, w2f);
    prep_z<<<(NROWS * 8) / 256, 256, 0, stream>>>(z_old, DA, S);

    step_kernel<1, 0><<<STEPGRID, 256, 0, stream>>>(DA, DB, S, z_old, out, nl, b1, b2, wf, w2f);
    step_kernel<0, 0><<<STEPGRID, 256, 0, stream>>>(DB, DA, S, z_old, out, nl, b1, b2, wf, w2f);
    step_kernel<0, 0><<<STEPGRID, 256, 0, stream>>>(DA, DB, S, z_old, out, nl, b1, b2, wf, w2f);
    step_kernel<0, 1><<<STEPGRID, 256, 0, stream>>>(DB, DA, S, z_old, out, nl, b1, b2, wf, w2f);
  } else {
    // ---- round-1 fallback ----
    u16* wf = (u16*)d_ws;
    u16* w2t = wf + 32768;
    const size_t zoff = 73728;
    const size_t zbytes = (size_t)NROWS * DLAT * sizeof(float);
    prep_old<<<72, 256, 0, stream>>>(W1, W2, wf, w2t);
    if (ws_size >= zoff + zbytes) {
      float* zbuf = (float*)((char*)d_ws + zoff);
      step_old<<<STEPGRID, 256, 0, stream>>>(z_old, zbuf, nl, b1, b2, wf, w2t);
      step_old<<<STEPGRID, 256, 0, stream>>>(zbuf, out, nl, b1, b2, wf, w2t);
      step_old<<<STEPGRID, 256, 0, stream>>>(out, zbuf, nl, b1, b2, wf, w2t);
      step_old<<<STEPGRID, 256, 0, stream>>>(zbuf, out, nl, b1, b2, wf, w2t);
    } else {
      float* zmut = (float*)d_in[0];
      step_old<<<STEPGRID, 256, 0, stream>>>(z_old, out, nl, b1, b2, wf, w2t);
      step_old<<<STEPGRID, 256, 0, stream>>>(out, zmut, nl, b1, b2, wf, w2t);
      step_old<<<STEPGRID, 256, 0, stream>>>(zmut, out, nl, b1, b2, wf, w2t);
      step_old<<<STEPGRID, 256, 0, stream>>>(out, zmut, nl, b1, b2, wf, w2t);
      hipMemcpyAsync(out, zmut, zbytes, hipMemcpyDeviceToDevice, stream);
    }
  }
}

// Round 4
// 362.318 us; speedup vs baseline: 1.1557x; 1.1557x over previous
//
#include <hip/hip_runtime.h>
#include <hip/hip_bf16.h>

typedef unsigned short u16;
typedef unsigned int u32;
typedef __attribute__((ext_vector_type(8))) short bf16x8;
typedef __attribute__((ext_vector_type(4))) float f32x4;
typedef __attribute__((ext_vector_type(4))) u16 u16x4;

#define NPATCH 81920
#define NBATCH 4
#define NROWS (NBATCH * NPATCH)   // 327680
#define HID 128
#define CHUNK 64
#define NCHUNK (NROWS / CHUNK)    // 5120
#define CPB (NPATCH / CHUNK)      // 1280
#define GSTRIDE 512               // 2 blocks/CU * 256 CUs

// ---------- conversion helpers (RNE) ----------
__device__ __forceinline__ u16 f2bf(float x) {
  union { __hip_bfloat16 b; u16 u; } c; c.b = __float2bfloat16(x); return c.u;
}
__device__ __forceinline__ float bf2f(u16 h) {
  union { __hip_bfloat16 b; u16 u; } c; c.u = h; return __bfloat162float(c.b);
}

// async global->LDS DMA, 16B/lane, dest = wave-uniform base + lane*16
#define GLD(g, l) __builtin_amdgcn_global_load_lds( \
    (const __attribute__((address_space(1))) void*)(g), \
    (__attribute__((address_space(3))) void*)(l), 16, 0, 0)
#define SBAR() __builtin_amdgcn_s_barrier()
#define SCHED0() __builtin_amdgcn_sched_barrier(0)

// ---------------- weight prep (layouts identical to round 3, verified) ----------------
// wf  : [part(2)][kg(16)][n(128)][j(8)]  (k' = kg*8+j = s*32+d -> W1 row d*4+s)
// w2f : [part(2)][kt(4)][lg(4)][o(16)][j(8)]
__global__ void prep_w(const float* __restrict__ W1, const float* __restrict__ W2,
                       u16* __restrict__ wf, u16* __restrict__ w2f) {
  int t = blockIdx.x * 256 + threadIdx.x;
  if (t < 128 * 128) {
    int kp = t >> 7, n = t & 127;
    int s = kp >> 5, d = kp & 31;
    float v = W1[(d * 4 + s) * HID + n];
    u16 h = f2bf(v);
    u16 l = f2bf(v - bf2f(h));
    int kg = kp >> 3, j = kp & 7;
    int o = (kg * 128 + n) * 8 + j;
    wf[o] = h;
    wf[16384 + o] = l;
  } else if (t < 128 * 128 + 2048) {
    int u = t - 128 * 128;            // u = k*16 + o
    int k = u >> 4, o = u & 15;
    float v = W2[k * 16 + o];
    u16 h = f2bf(v);
    u16 l = f2bf(v - bf2f(h));
    int kt = k >> 5, lg = (k >> 3) & 3, j = k & 7;
    int idx = ((kt * 4 + lg) * 16 + o) * 8 + j;
    w2f[idx] = h;
    w2f[2048 + idx] = l;
  }
}

// z split. MERGED: 128B rows [d0-15 hi|d0-15 lo|d16-31 hi|d16-31 lo] written to BOTH A0,B0.
// else: A0 = dynamic 64B rows [hi16|lo16], B0 = static 64B rows [hi16|lo16].
template<int MERGED>
__global__ void prep_z(const float* __restrict__ z, u16* __restrict__ A0, u16* __restrict__ B0) {
  int t = blockIdx.x * 256 + threadIdx.x;
  if (t >= NROWS * 8) return;
  size_t row = (size_t)(t >> 3);
  int q = t & 7;                       // dim quad 0..7
  float4 v = *(const float4*)&z[row * 32 + q * 4];
  u16 h0 = f2bf(v.x), h1 = f2bf(v.y), h2 = f2bf(v.z), h3 = f2bf(v.w);
  u16 l0 = f2bf(v.x - bf2f(h0)), l1 = f2bf(v.y - bf2f(h1));
  u16 l2 = f2bf(v.z - bf2f(h2)), l3 = f2bf(v.w - bf2f(h3));
  u16x4 hh = {h0, h1, h2, h3};
  u16x4 ll = {l0, l1, l2, l3};
  int dd = (q & 3) * 4;
  if (MERGED) {
    int reg = (q < 4) ? 0 : 32;
    *(u16x4*)&A0[row * 64 + reg + dd] = hh;
    *(u16x4*)&A0[row * 64 + reg + 16 + dd] = ll;
    *(u16x4*)&B0[row * 64 + reg + dd] = hh;
    *(u16x4*)&B0[row * 64 + reg + 16 + dd] = ll;
  } else {
    u16* buf = (q < 4) ? A0 : B0;
    *(u16x4*)&buf[row * 32 + dd] = hh;
    *(u16x4*)&buf[row * 32 + 16 + dd] = ll;
  }
}

// ---------------- one solver step, software-pipelined ----------------
template<int FIRST, int LAST, int MERGED>
__global__ __launch_bounds__(256, 2) void step_kernel(
    const u16* __restrict__ Zin, u16* __restrict__ Zout,
    const u16* __restrict__ Sst,
    const float* __restrict__ zold, float* __restrict__ zf,
    const int* __restrict__ nl, const float* __restrict__ b1,
    const float* __restrict__ b2, const u16* __restrict__ wf,
    const u16* __restrict__ w2f) {
  // double-buffered A/h tiles, fragment order [kg(16)][row(64)][j(8)]
  __shared__ __align__(16) u16 AH[2][16 * 64 * 8];   // 2 x 16 KB
  __shared__ __align__(16) u16 AL[2][16 * 64 * 8];   // 2 x 16 KB
  __shared__ __align__(16) u16 W2H[2048];            // 4 KB
  __shared__ __align__(16) u16 W2L[2048];            // 4 KB

  const int tid = threadIdx.x;
  const int lane = tid & 63;
  const int w = tid >> 6;
  const int li = lane & 15;
  const int lg = lane >> 4;

  // stage W2 fragments (512 slot copies of 8 elems)
  #pragma unroll
  for (int c = 0; c < 2; ++c) {
    int idx = tid + c * 256;
    int part = idx >> 8, slot = idx & 255;
    u16* dst = part ? W2L : W2H;
    *(bf16x8*)&dst[slot * 8] = *(const bf16x8*)&w2f[part * 2048 + slot * 8];
  }

  // W1 fragments resident in registers: wave w owns cols [32w, 32w+32)
  bf16x8 WH[2][4], WL[2][4];
  #pragma unroll
  for (int nt = 0; nt < 2; ++nt)
    #pragma unroll
    for (int kt = 0; kt < 4; ++kt) {
      int kg = kt * 4 + lg;
      int n = w * 32 + nt * 16 + li;
      WH[nt][kt] = *(const bf16x8*)&wf[(kg * 128 + n) * 8];
      WL[nt][kt] = *(const bf16x8*)&wf[16384 + (kg * 128 + n) * 8];
    }

  float b1v[2][4];
  #pragma unroll
  for (int nt = 0; nt < 2; ++nt)
    #pragma unroll
    for (int r = 0; r < 4; ++r)
      b1v[nt][r] = b1[w * 32 + nt * 16 + lg * 4 + r];
  float b2v = b2[li];

  // per-lane nl index for chunk CN (w>0 only)
  #define NVLOAD(CN) nl[(((CN) * CHUNK - ((CN) / CPB) * NPATCH) + lane) * 3 + (w - 1)]

  // issue 8 GLDs for chunk CN into buffer BUF (wave w = source section, lane = row)
  #define STAGE(BUF, CN, NV) do {                                          \
    int b_ = (CN) / CPB;                                                   \
    int pb_ = (CN) * CHUNK - b_ * NPATCH;                                  \
    int ps_ = w ? (NV) : (pb_ + lane);                                     \
    size_t r_ = (size_t)b_ * NPATCH + (size_t)ps_;                         \
    u16* ah_ = &AH[BUF][(w * 4) * 512];                                    \
    u16* al_ = &AL[BUF][(w * 4) * 512];                                    \
    if (MERGED) {                                                          \
      const u16* s_ = Zin + r_ * 64;                                       \
      GLD(s_ + 0,  ah_ + 0);    GLD(s_ + 8,  ah_ + 512);                   \
      GLD(s_ + 32, ah_ + 1024); GLD(s_ + 40, ah_ + 1536);                  \
      GLD(s_ + 16, al_ + 0);    GLD(s_ + 24, al_ + 512);                   \
      GLD(s_ + 48, al_ + 1024); GLD(s_ + 56, al_ + 1536);                  \
    } else {                                                               \
      const u16* d_ = Zin + r_ * 32;                                       \
      const u16* t_ = Sst + r_ * 32;                                       \
      GLD(d_ + 0,  ah_ + 0);    GLD(d_ + 8,  ah_ + 512);                   \
      GLD(t_ + 0,  ah_ + 1024); GLD(t_ + 8,  ah_ + 1536);                  \
      GLD(d_ + 16, al_ + 0);    GLD(d_ + 24, al_ + 512);                   \
      GLD(t_ + 16, al_ + 1024); GLD(t_ + 24, al_ + 1536);                  \
    }                                                                      \
  } while (0)

  // ---- prologue: nl(c0), nl(c1) issued BEFORE chunk-0 GLDs (FIFO discipline) ----
  int c0 = blockIdx.x;
  int nv = 0, nv1 = 0;
  if (w) nv = NVLOAD(c0);
  {
    int c1 = c0 + GSTRIDE; if (c1 > NCHUNK - 1) c1 = NCHUNK - 1;
    if (w) nv1 = NVLOAD(c1);
  }
  STAGE(0, c0, nv);
  asm volatile("s_waitcnt lgkmcnt(0)" ::: "memory");  // W2 ds_writes retired
  int cur = 0;

  for (int c = c0; c < NCHUNK; c += GSTRIDE) {
    int cn = c + GSTRIDE;
    bool hn = cn < NCHUNK;
    // stage next chunk (8 GLDs), then prefetch nl two chunks ahead
    if (hn) STAGE(cur ^ 1, cn, nv1);
    {
      int cnn = cn + GSTRIDE; if (cnn > NCHUNK - 1) cnn = NCHUNK - 1;
      if (w && hn) nv1 = NVLOAD(cnn);
    }
    // counted wait: retire current chunk's GLDs, keep next chunk's 8 (+nl) in flight
    if (!hn)        { asm volatile("s_waitcnt vmcnt(0)" ::: "memory"); }
    else if (w == 0){ asm volatile("s_waitcnt vmcnt(8)" ::: "memory"); }
    else            { asm volatile("s_waitcnt vmcnt(9)" ::: "memory"); }
    SCHED0(); SBAR(); SCHED0();

    // ---- GEMM1 (transposed): D[n][m] = W1^T @ A^T, bf16x3 split ----
    f32x4 acc[2][4];
    #pragma unroll
    for (int nt = 0; nt < 2; ++nt)
      #pragma unroll
      for (int mt = 0; mt < 4; ++mt)
        acc[nt][mt] = (f32x4){0.f, 0.f, 0.f, 0.f};

    #pragma unroll
    for (int kt = 0; kt < 4; ++kt) {
      #pragma unroll
      for (int mt = 0; mt < 4; ++mt) {
        int off = ((kt * 4 + lg) * 64 + mt * 16 + li) * 8;
        bf16x8 ah = *(const bf16x8*)&AH[cur][off];
        bf16x8 al = *(const bf16x8*)&AL[cur][off];
        #pragma unroll
        for (int nt = 0; nt < 2; ++nt) {
          acc[nt][mt] = __builtin_amdgcn_mfma_f32_16x16x32_bf16(WH[nt][kt], ah, acc[nt][mt], 0, 0, 0);
          acc[nt][mt] = __builtin_amdgcn_mfma_f32_16x16x32_bf16(WH[nt][kt], al, acc[nt][mt], 0, 0, 0);
          acc[nt][mt] = __builtin_amdgcn_mfma_f32_16x16x32_bf16(WL[nt][kt], ah, acc[nt][mt], 0, 0, 0);
        }
      }
    }
    SCHED0(); SBAR(); SCHED0();   // all A reads done before h overwrites

    // ---- bias + tanh + split -> h fragments (overwrite AH/AL[cur]) ----
    #pragma unroll
    for (int nt = 0; nt < 2; ++nt) {
      #pragma unroll
      for (int mt = 0; mt < 4; ++mt) {
        u16 hh[4], ll[4];
        #pragma unroll
        for (int r = 0; r < 4; ++r) {
          float hval = acc[nt][mt][r] + b1v[nt][r];
          float e = __expf(2.0f * hval);
          float t = 1.0f - 2.0f / (e + 1.0f);
          hh[r] = f2bf(t);
          ll[r] = f2bf(t - bf2f(hh[r]));
        }
        // n = w*32+nt*16+lg*4+r -> [kg2=n>>3][row=m][j=n&7]
        int base = ((w * 4 + nt * 2 + (lg >> 1)) * 64 + mt * 16 + li) * 8 + (lg & 1) * 4;
        u16x4 hv = {hh[0], hh[1], hh[2], hh[3]};
        u16x4 lv = {ll[0], ll[1], ll[2], ll[3]};
        *(u16x4*)&AH[cur][base] = hv;
        *(u16x4*)&AL[cur][base] = lv;
      }
    }
    asm volatile("s_waitcnt lgkmcnt(0)" ::: "memory");  // h writes retired
    SCHED0(); SBAR(); SCHED0();

    // ---- GEMM2: F[m][o] = h @ W2, bf16x3 split; wave w owns rows [16w,16w+16) ----
    f32x4 acc2 = (f32x4){0.f, 0.f, 0.f, 0.f};
    #pragma unroll
    for (int kt = 0; kt < 4; ++kt) {
      int woff = ((kt * 4 + lg) * 16 + li) * 8;
      bf16x8 wh = *(const bf16x8*)&W2H[woff];
      bf16x8 wl = *(const bf16x8*)&W2L[woff];
      int off = ((kt * 4 + lg) * 64 + w * 16 + li) * 8;
      bf16x8 hh = *(const bf16x8*)&AH[cur][off];
      bf16x8 hl = *(const bf16x8*)&AL[cur][off];
      acc2 = __builtin_amdgcn_mfma_f32_16x16x32_bf16(hh, wh, acc2, 0, 0, 0);
      acc2 = __builtin_amdgcn_mfma_f32_16x16x32_bf16(hl, wh, acc2, 0, 0, 0);
      acc2 = __builtin_amdgcn_mfma_f32_16x16x32_bf16(hh, wl, acc2, 0, 0, 0);
    }

    // ---- epilogue: z_out[:, :16] = z_in[:, :16] + F ----
    #pragma unroll
    for (int r = 0; r < 4; ++r) {
      int rowg = c * CHUNK + w * 16 + lg * 4 + r;
      float F = acc2[r] + b2v;
      float zi = FIRST ? zold[(size_t)rowg * 32 + li] : zf[(size_t)rowg * 32 + li];
      float v = zi + F;
      zf[(size_t)rowg * 32 + li] = v;
      if (LAST) {
        zf[(size_t)rowg * 32 + 16 + li] = zold[(size_t)rowg * 32 + 16 + li];
      } else {
        u16 h = f2bf(v);
        u16 l = f2bf(v - bf2f(h));
        if (MERGED) {
          Zout[(size_t)rowg * 64 + li] = h;
          Zout[(size_t)rowg * 64 + 16 + li] = l;
        } else {
          Zout[(size_t)rowg * 32 + li] = h;
          Zout[(size_t)rowg * 32 + 16 + li] = l;
        }
      }
    }
    cur ^= 1;
  }
  #undef STAGE
  #undef NVLOAD
}

extern "C" void kernel_launch(void* const* d_in, const int* in_sizes, int n_in,
                              void* d_out, int out_size, void* d_ws, size_t ws_size,
                              hipStream_t stream) {
  const float* z_old = (const float*)d_in[0];
  const int* nl = (const int*)d_in[1];
  const float* W1 = (const float*)d_in[2];
  const float* b1 = (const float*)d_in[3];
  const float* W2 = (const float*)d_in[4];
  const float* b2 = (const float*)d_in[5];
  float* out = (float*)d_out;

  const size_t wOff = 73728;
  const size_t DbM = (size_t)NROWS * 64 * sizeof(u16);   // 40 MB merged row buffer
  const size_t DbS = (size_t)NROWS * 32 * sizeof(u16);   // 20 MB split buffer
  const size_t needM = wOff + 2 * DbM;                   // ~84 MB
  u16* wf = (u16*)d_ws;                                  // 64 KB
  u16* w2f = wf + 32768;                                 // 8 KB
  char* base = (char*)d_ws + wOff;

  prep_w<<<72, 256, 0, stream>>>(W1, W2, wf, w2f);

  if (ws_size >= needM) {
    u16* ZA = (u16*)base;
    u16* ZB = (u16*)(base + DbM);
    prep_z<1><<<(NROWS * 8) / 256, 256, 0, stream>>>(z_old, ZA, ZB);
    step_kernel<1, 0, 1><<<GSTRIDE, 256, 0, stream>>>(ZA, ZB, nullptr, z_old, out, nl, b1, b2, wf, w2f);
    step_kernel<0, 0, 1><<<GSTRIDE, 256, 0, stream>>>(ZB, ZA, nullptr, z_old, out, nl, b1, b2, wf, w2f);
    step_kernel<0, 0, 1><<<GSTRIDE, 256, 0, stream>>>(ZA, ZB, nullptr, z_old, out, nl, b1, b2, wf, w2f);
    step_kernel<0, 1, 1><<<GSTRIDE, 256, 0, stream>>>(ZB, ZA, nullptr, z_old, out, nl, b1, b2, wf, w2f);
  } else {
    // split fallback (round-3 buffer sizes, known to fit: ~60.1 MB)
    u16* S  = (u16*)base;
    u16* DA = (u16*)(base + DbS);
    u16* DB = (u16*)(base + 2 * DbS);
    prep_z<0><<<(NROWS * 8) / 256, 256, 0, stream>>>(z_old, DA, S);
    step_kernel<1, 0, 0><<<GSTRIDE, 256, 0, stream>>>(DA, DB, S, z_old, out, nl, b1, b2, wf, w2f);
    step_kernel<0, 0, 0><<<GSTRIDE, 256, 0, stream>>>(DB, DA, S, z_old, out, nl, b1, b2, wf, w2f);
    step_kernel<0, 0, 0><<<GSTRIDE, 256, 0, stream>>>(DA, DB, S, z_old, out, nl, b1, b2, wf, w2f);
    step_kernel<0, 1, 0><<<GSTRIDE, 256, 0, stream>>>(DB, DA, S, z_old, out, nl, b1, b2, wf, w2f);
  }
}